// Round 1
// baseline (17126.932 us; speedup 1.0000x reference)
//
#include <hip/hip_runtime.h>
#include <stdint.h>

#define D 512
#define T 2048      // S * var_num = 8 * 256
#define VOCAB 32000
#define NWG 16      // LSTM workgroups

typedef __attribute__((ext_vector_type(8))) short short8;
typedef __attribute__((ext_vector_type(4))) float f32x4;
typedef __attribute__((ext_vector_type(8))) unsigned short u16x8;

__device__ __forceinline__ float fast_rcp(float x) { return __builtin_amdgcn_rcpf(x); }
__device__ __forceinline__ float sigm(float x) { return fast_rcp(1.0f + __expf(-x)); }
__device__ __forceinline__ float tanh_fast(float x) {
  float e = __expf(2.0f * x);
  return 1.0f - 2.0f * fast_rcp(e + 1.0f);  // saturates correctly at +-1, no NaN
}
__device__ __forceinline__ unsigned short f2bf(float f) {  // RTNE float->bf16
  unsigned u = __float_as_uint(f);
  unsigned r = u + 0x7fffu + ((u >> 16) & 1u);
  return (unsigned short)(r >> 16);
}

// ---------------------------------------------------------------------------
// Kernel 1: merged = ctx @ Wm + bm ; xz = merged @ W + b   (per 4-row block)
// x_seq is merged tiled 8x, so xz only needs the 256 base rows.
// ---------------------------------------------------------------------------
__global__ __launch_bounds__(512) void prep_kernel(
    const float* __restrict__ ctx, const float* __restrict__ Wm,
    const float* __restrict__ bm, const float* __restrict__ W,
    const float* __restrict__ b, float* __restrict__ xz)
{
  __shared__ float ctx_s[4][1024];
  __shared__ float mg_s[4][512];
  const int tid = threadIdx.x;
  const int r0 = blockIdx.x * 4;

  for (int i = tid; i < 1024; i += 512) {  // 4 rows * 256 float4 chunks
    int rr = i >> 8, c4 = (i & 255) * 4;
    *(float4*)&ctx_s[rr][c4] = *(const float4*)&ctx[(size_t)(r0 + rr) * 1024 + c4];
  }
  __syncthreads();
  {  // merged: thread -> (row rr, 4 consecutive cols)
    const int rr = tid >> 7, cg = (tid & 127) * 4;
    float a0 = bm[cg], a1 = bm[cg + 1], a2 = bm[cg + 2], a3 = bm[cg + 3];
    for (int k = 0; k < 1024; k += 4) {
      float4 cv = *(float4*)&ctx_s[rr][k];
      #pragma unroll
      for (int kk = 0; kk < 4; kk++) {
        float cc = (kk == 0) ? cv.x : (kk == 1) ? cv.y : (kk == 2) ? cv.z : cv.w;
        float4 wv = *(const float4*)&Wm[(size_t)(k + kk) * 512 + cg];
        a0 += cc * wv.x; a1 += cc * wv.y; a2 += cc * wv.z; a3 += cc * wv.w;
      }
    }
    *(float4*)&mg_s[rr][cg] = make_float4(a0, a1, a2, a3);
  }
  __syncthreads();
  {  // xz: thread -> (row rr, 16 consecutive cols of 2048)
    const int rr = tid >> 7, cg = (tid & 127) * 16;
    float acc[16];
    #pragma unroll
    for (int c = 0; c < 16; c++) acc[c] = b[cg + c];
    for (int k = 0; k < 512; k += 4) {
      float4 mv = *(float4*)&mg_s[rr][k];
      #pragma unroll
      for (int kk = 0; kk < 4; kk++) {
        float cc = (kk == 0) ? mv.x : (kk == 1) ? mv.y : (kk == 2) ? mv.z : mv.w;
        #pragma unroll
        for (int c4 = 0; c4 < 4; c4++) {
          float4 wv = *(const float4*)&W[(size_t)(k + kk) * 2048 + cg + c4 * 4];
          acc[c4 * 4 + 0] += cc * wv.x; acc[c4 * 4 + 1] += cc * wv.y;
          acc[c4 * 4 + 2] += cc * wv.z; acc[c4 * 4 + 3] += cc * wv.w;
        }
      }
    }
    #pragma unroll
    for (int c4 = 0; c4 < 4; c4++)
      *(float4*)&xz[(size_t)(r0 + rr) * 2048 + cg + c4 * 4] =
          make_float4(acc[c4 * 4], acc[c4 * 4 + 1], acc[c4 * 4 + 2], acc[c4 * 4 + 3]);
  }
}

// ---------------------------------------------------------------------------
// Kernel 2: Wlt[c][k] = bf16(Wl[k][c])  (transposed + converted for MFMA B)
// ---------------------------------------------------------------------------
__global__ __launch_bounds__(256) void wl_convert_kernel(
    const float* __restrict__ Wl, unsigned short* __restrict__ Wlt)
{
  const int c = blockIdx.x * 256 + threadIdx.x;
  for (int k8 = 0; k8 < 64; k8++) {
    u16x8 v;
    #pragma unroll
    for (int e = 0; e < 8; e++)
      v[e] = f2bf(Wl[(size_t)(k8 * 8 + e) * VOCAB + c]);
    *(u16x8*)&Wlt[(size_t)c * 512 + k8 * 8] = v;
  }
}

// ---------------------------------------------------------------------------
// Kernel 3: sequential LSTM over T steps. 16 WGs x 512 threads (cooperative).
// WG p owns units [32p,32p+32): 128 U-columns register-resident (u[16][8]).
// thread: rb = tid&31 -> rows rb*16..+15 ; cb = tid>>5 -> local cols cb*8..+7
// Cross-WG h exchange: packed u64 {counter=t+1 | f32 h bits}, agent-scope
// atomics through L3, double-buffered by step parity. No separate flag.
// ---------------------------------------------------------------------------
__global__ __launch_bounds__(512, 2) void lstm_kernel(
    const float* __restrict__ xz, const float* __restrict__ U,
    uint64_t* __restrict__ hb, unsigned short* __restrict__ hs)
{
  __shared__ float z_lds[2][128];
  const int tid = threadIdx.x;
  const int wg = blockIdx.x;
  const int rb = tid & 31;
  const int cb = tid >> 5;
  const int gate = cb >> 2;
  const int gcol0 = gate * 512 + wg * 32 + (cb & 3) * 8;

  float u[16][8];
  #pragma unroll
  for (int e = 0; e < 16; e++) {
    const float* up = &U[(size_t)(rb * 16 + e) * 2048 + gcol0];
    float4 w0 = *(const float4*)up;
    float4 w1 = *(const float4*)(up + 4);
    u[e][0] = w0.x; u[e][1] = w0.y; u[e][2] = w0.z; u[e][3] = w0.w;
    u[e][4] = w1.x; u[e][5] = w1.y; u[e][6] = w1.z; u[e][7] = w1.w;
  }

  float creg = 0.0f;
  const int hbase = rb * 16;

  for (int t = 0; t < T; t++) {
    float xzv0, xzv1, xzv2, xzv3;
    if (tid < 32) {  // prefetch this step's xz (independent of h)
      const float* xp = &xz[(size_t)(t & 255) * 2048 + wg * 32 + tid];
      xzv0 = xp[0]; xzv1 = xp[512]; xzv2 = xp[1024]; xzv3 = xp[1536];
    }
    // poll + load h_t rows [rb*16, rb*16+16)
    const uint64_t* hcur = hb + (size_t)(t & 1) * 512 + hbase;
    float hv[16];
    for (;;) {
      uint64_t wv[16];
      #pragma unroll
      for (int e = 0; e < 16; e++)
        wv[e] = __hip_atomic_load(&hcur[e], __ATOMIC_RELAXED, __HIP_MEMORY_SCOPE_AGENT);
      bool ok = true;
      #pragma unroll
      for (int e = 0; e < 16; e++)
        ok &= ((unsigned)(wv[e] >> 32) == (unsigned)t);
      if (ok) {
        #pragma unroll
        for (int e = 0; e < 16; e++) hv[e] = __uint_as_float((unsigned)wv[e]);
        break;
      }
    }
    // partial matvec for this thread's 16 rows x 8 cols
    float zp[8];
    #pragma unroll
    for (int c = 0; c < 8; c++) zp[c] = 0.0f;
    #pragma unroll
    for (int e = 0; e < 16; e++) {
      #pragma unroll
      for (int c = 0; c < 8; c++) zp[c] += hv[e] * u[e][c];
    }
    // reduce over the 32 threads sharing cb (xor masks stay in 32-lane group)
    #pragma unroll
    for (int m = 1; m < 32; m <<= 1) {
      #pragma unroll
      for (int c = 0; c < 8; c++) zp[c] += __shfl_xor(zp[c], m, 64);
    }
    const int par = t & 1;
    if (rb == 0) {
      *(float4*)&z_lds[par][cb * 8]     = make_float4(zp[0], zp[1], zp[2], zp[3]);
      *(float4*)&z_lds[par][cb * 8 + 4] = make_float4(zp[4], zp[5], zp[6], zp[7]);
    }
    __syncthreads();
    if (tid < 32) {  // gates for unit u = tid
      float zi = z_lds[par][tid]       + xzv0;
      float zf = z_lds[par][32 + tid]  + xzv1;
      float zg = z_lds[par][64 + tid]  + xzv2;
      float zo = z_lds[par][96 + tid]  + xzv3;
      float ig = sigm(zi), fg = sigm(zf), gg = tanh_fast(zg), og = sigm(zo);
      creg = fg * creg + ig * gg;
      float h = og * tanh_fast(creg);
      hs[(size_t)t * 512 + wg * 32 + tid] = f2bf(h);
      uint64_t pk = ((uint64_t)(unsigned)(t + 1) << 32) | (uint64_t)__float_as_uint(h);
      __hip_atomic_store(&hb[(size_t)((t + 1) & 1) * 512 + wg * 32 + tid], pk,
                         __ATOMIC_RELAXED, __HIP_MEMORY_SCOPE_AGENT);
    }
  }
}

// ---------------------------------------------------------------------------
// Kernel 4: logits = hs @ Wl + bl, bf16 MFMA 16x16x32, 128x128 tile, 4 waves.
// Output remap: gemm row t -> out row (t%256)*8 + t/256.
// ---------------------------------------------------------------------------
__global__ __launch_bounds__(256) void logits_kernel(
    const unsigned short* __restrict__ hs, const unsigned short* __restrict__ Wlt,
    const float* __restrict__ bl, float* __restrict__ out)
{
  __shared__ unsigned short As[128][40];  // [row][k] +8 pad
  __shared__ unsigned short Bs[128][40];  // [col][k] +8 pad
  const int tid = threadIdx.x;
  const int bx = blockIdx.x, by = blockIdx.y;
  const int lane = tid & 63, w = tid >> 6;
  const int wr = w >> 1, wc = w & 1;

  f32x4 acc[4][4];
  #pragma unroll
  for (int i = 0; i < 4; i++) {
    #pragma unroll
    for (int j = 0; j < 4; j++) acc[i][j] = (f32x4){0.0f, 0.0f, 0.0f, 0.0f};
  }

  for (int kk = 0; kk < 512; kk += 32) {
    #pragma unroll
    for (int i = 0; i < 2; i++) {
      int chunk = tid * 2 + i;          // 512 chunks of 16B
      int r = chunk >> 2, c8 = (chunk & 3) * 8;
      *(uint4*)&As[r][c8] = *(const uint4*)&hs[(size_t)(by * 128 + r) * 512 + kk + c8];
      *(uint4*)&Bs[r][c8] = *(const uint4*)&Wlt[(size_t)(bx * 128 + r) * 512 + kk + c8];
    }
    __syncthreads();
    short8 af[4], bf[4];
    #pragma unroll
    for (int fr = 0; fr < 4; fr++)
      af[fr] = *(const short8*)&As[wr * 64 + fr * 16 + (lane & 15)][(lane >> 4) * 8];
    #pragma unroll
    for (int fc = 0; fc < 4; fc++)
      bf[fc] = *(const short8*)&Bs[wc * 64 + fc * 16 + (lane & 15)][(lane >> 4) * 8];
    #pragma unroll
    for (int fr = 0; fr < 4; fr++) {
      #pragma unroll
      for (int fc = 0; fc < 4; fc++)
        acc[fr][fc] = __builtin_amdgcn_mfma_f32_16x16x32_bf16(af[fr], bf[fc], acc[fr][fc], 0, 0, 0);
    }
    __syncthreads();
  }

  #pragma unroll
  for (int fc = 0; fc < 4; fc++) {
    int col = bx * 128 + wc * 64 + fc * 16 + (lane & 15);
    float blv = bl[col];
    #pragma unroll
    for (int fr = 0; fr < 4; fr++) {
      int row0 = by * 128 + wr * 64 + fr * 16 + (lane >> 4) * 4;
      #pragma unroll
      for (int j = 0; j < 4; j++) {
        int row = row0 + j;
        int orow = (row & 255) * 8 + (row >> 8);
        out[(size_t)orow * VOCAB + col] = acc[fr][fc][j] + blv;
      }
    }
  }
}

// ---------------------------------------------------------------------------
extern "C" void kernel_launch(void* const* d_in, const int* in_sizes, int n_in,
                              void* d_out, int out_size, void* d_ws, size_t ws_size,
                              hipStream_t stream)
{
  const float* ctx = (const float*)d_in[0];
  const float* Wm  = (const float*)d_in[1];
  const float* bm  = (const float*)d_in[2];
  const float* W   = (const float*)d_in[3];
  const float* U   = (const float*)d_in[4];
  const float* b   = (const float*)d_in[5];
  const float* Wl  = (const float*)d_in[6];
  const float* bl  = (const float*)d_in[7];
  float* out = (float*)d_out;

  char* ws = (char*)d_ws;
  uint64_t* hb        = (uint64_t*)ws;                                  // 8 KB (2x512 u64)
  float* xz           = (float*)(ws + 65536);                           // 2 MB
  unsigned short* hs  = (unsigned short*)(ws + 65536 + (1 << 21));      // 2 MB
  unsigned short* Wlt = (unsigned short*)(ws + 65536 + (2 << 21));      // 32.77 MB

  hipMemsetAsync(hb, 0, 8192, stream);  // h_0 = 0 with counter 0 (both parities)
  prep_kernel<<<dim3(64), dim3(512), 0, stream>>>(ctx, Wm, bm, W, b, xz);
  wl_convert_kernel<<<dim3(125), dim3(256), 0, stream>>>(Wl, Wlt);

  void* args[] = { (void*)&xz, (void*)&U, (void*)&hb, (void*)&hs };
  hipLaunchCooperativeKernel((void*)lstm_kernel, dim3(NWG), dim3(512), args, 0, stream);

  logits_kernel<<<dim3(250, 16), dim3(256), 0, stream>>>(hs, Wlt, bl, out);
}

// Round 2
// 4873.901 us; speedup vs baseline: 3.5140x; 3.5140x over previous
//
#include <hip/hip_runtime.h>
#include <stdint.h>

#define D 512
#define T 2048      // S * var_num = 8 * 256
#define VOCAB 32000
#define NWG 16      // LSTM workgroups

typedef __attribute__((ext_vector_type(8))) short short8;
typedef __attribute__((ext_vector_type(4))) float f32x4;
typedef __attribute__((ext_vector_type(8))) unsigned short u16x8;

__device__ __forceinline__ float fast_rcp(float x) { return __builtin_amdgcn_rcpf(x); }
__device__ __forceinline__ float sigm(float x) { return fast_rcp(1.0f + __expf(-x)); }
__device__ __forceinline__ float tanh_fast(float x) {
  float e = __expf(2.0f * x);
  return 1.0f - 2.0f * fast_rcp(e + 1.0f);  // saturates correctly at +-1, no NaN
}
__device__ __forceinline__ unsigned short f2bf(float f) {  // RTNE float->bf16
  unsigned u = __float_as_uint(f);
  unsigned r = u + 0x7fffu + ((u >> 16) & 1u);
  return (unsigned short)(r >> 16);
}

// ---------------------------------------------------------------------------
// Kernel 1: merged = ctx @ Wm + bm ; xz = merged @ W + b   (per 4-row block)
// x_seq is merged tiled 8x, so xz only needs the 256 base rows.
// ---------------------------------------------------------------------------
__global__ __launch_bounds__(512) void prep_kernel(
    const float* __restrict__ ctx, const float* __restrict__ Wm,
    const float* __restrict__ bm, const float* __restrict__ W,
    const float* __restrict__ b, float* __restrict__ xz)
{
  __shared__ float ctx_s[4][1024];
  __shared__ float mg_s[4][512];
  const int tid = threadIdx.x;
  const int r0 = blockIdx.x * 4;

  for (int i = tid; i < 1024; i += 512) {  // 4 rows * 256 float4 chunks
    int rr = i >> 8, c4 = (i & 255) * 4;
    *(float4*)&ctx_s[rr][c4] = *(const float4*)&ctx[(size_t)(r0 + rr) * 1024 + c4];
  }
  __syncthreads();
  {  // merged: thread -> (row rr, 4 consecutive cols)
    const int rr = tid >> 7, cg = (tid & 127) * 4;
    float a0 = bm[cg], a1 = bm[cg + 1], a2 = bm[cg + 2], a3 = bm[cg + 3];
    for (int k = 0; k < 1024; k += 4) {
      float4 cv = *(float4*)&ctx_s[rr][k];
      #pragma unroll
      for (int kk = 0; kk < 4; kk++) {
        float cc = (kk == 0) ? cv.x : (kk == 1) ? cv.y : (kk == 2) ? cv.z : cv.w;
        float4 wv = *(const float4*)&Wm[(size_t)(k + kk) * 512 + cg];
        a0 += cc * wv.x; a1 += cc * wv.y; a2 += cc * wv.z; a3 += cc * wv.w;
      }
    }
    *(float4*)&mg_s[rr][cg] = make_float4(a0, a1, a2, a3);
  }
  __syncthreads();
  {  // xz: thread -> (row rr, 16 consecutive cols of 2048)
    const int rr = tid >> 7, cg = (tid & 127) * 16;
    float acc[16];
    #pragma unroll
    for (int c = 0; c < 16; c++) acc[c] = b[cg + c];
    for (int k = 0; k < 512; k += 4) {
      float4 mv = *(float4*)&mg_s[rr][k];
      #pragma unroll
      for (int kk = 0; kk < 4; kk++) {
        float cc = (kk == 0) ? mv.x : (kk == 1) ? mv.y : (kk == 2) ? mv.z : mv.w;
        #pragma unroll
        for (int c4 = 0; c4 < 4; c4++) {
          float4 wv = *(const float4*)&W[(size_t)(k + kk) * 2048 + cg + c4 * 4];
          acc[c4 * 4 + 0] += cc * wv.x; acc[c4 * 4 + 1] += cc * wv.y;
          acc[c4 * 4 + 2] += cc * wv.z; acc[c4 * 4 + 3] += cc * wv.w;
        }
      }
    }
    #pragma unroll
    for (int c4 = 0; c4 < 4; c4++)
      *(float4*)&xz[(size_t)(r0 + rr) * 2048 + cg + c4 * 4] =
          make_float4(acc[c4 * 4], acc[c4 * 4 + 1], acc[c4 * 4 + 2], acc[c4 * 4 + 3]);
  }
}

// ---------------------------------------------------------------------------
// Kernel 2: Wlt[c][k] = bf16(Wl[k][c])  (transposed + converted for MFMA B)
// ---------------------------------------------------------------------------
__global__ __launch_bounds__(256) void wl_convert_kernel(
    const float* __restrict__ Wl, unsigned short* __restrict__ Wlt)
{
  const int c = blockIdx.x * 256 + threadIdx.x;
  for (int k8 = 0; k8 < 64; k8++) {
    u16x8 v;
    #pragma unroll
    for (int e = 0; e < 8; e++)
      v[e] = f2bf(Wl[(size_t)(k8 * 8 + e) * VOCAB + c]);
    *(u16x8*)&Wlt[(size_t)c * 512 + k8 * 8] = v;
  }
}

// ---------------------------------------------------------------------------
// Kernel 3: sequential LSTM over T steps. 16 WGs x 512 threads (cooperative).
// WG p owns units [32p,32p+32): 128 U-columns register-resident (u[16][8]).
// thread: rb = tid&31 -> rows {rb + 32e, e=0..15} ; cb = tid>>5 -> 8 gate-cols
// Cross-WG h exchange: packed u64 {counter=t+1 | f32 h bits}, agent-scope
// atomics, double-buffered by step parity. Each thread polls EXACTLY ONE
// word (its tid's unit) then shares via LDS -> 16x less fabric traffic than
// everyone polling their own 16 rows (R1: 40 GB FETCH, 8.15 us/step).
// ---------------------------------------------------------------------------
__global__ __launch_bounds__(512, 2) void lstm_kernel(
    const float* __restrict__ xz, const float* __restrict__ U,
    uint64_t* __restrict__ hb, unsigned short* __restrict__ hs)
{
  __shared__ float h_lds[512];
  __shared__ float z_lds[128];
  const int tid = threadIdx.x;
  const int wg = blockIdx.x;
  const int rb = tid & 31;
  const int cb = tid >> 5;
  const int gate = cb >> 2;
  const int gcol0 = gate * 512 + wg * 32 + (cb & 3) * 8;

  // U rows {rb + 32e} x 8 gate-cols, register-resident
  float u[16][8];
  #pragma unroll
  for (int e = 0; e < 16; e++) {
    const float* up = &U[(size_t)(rb + 32 * e) * 2048 + gcol0];
    float4 w0 = *(const float4*)up;
    float4 w1 = *(const float4*)(up + 4);
    u[e][0] = w0.x; u[e][1] = w0.y; u[e][2] = w0.z; u[e][3] = w0.w;
    u[e][4] = w1.x; u[e][5] = w1.y; u[e][6] = w1.z; u[e][7] = w1.w;
  }

  float creg = 0.0f;

  for (int t = 0; t < T; t++) {
    float xzv0, xzv1, xzv2, xzv3;
    if (tid < 32) {  // prefetch this step's xz (independent of h)
      const float* xp = &xz[(size_t)(t & 255) * 2048 + wg * 32 + tid];
      xzv0 = xp[0]; xzv1 = xp[512]; xzv2 = xp[1024]; xzv3 = xp[1536];
    }
    // poll ONE word: unit `tid` of h_t
    {
      const uint64_t* hw = hb + (size_t)(t & 1) * 512 + tid;
      uint64_t wv;
      for (;;) {
        wv = __hip_atomic_load(hw, __ATOMIC_RELAXED, __HIP_MEMORY_SCOPE_AGENT);
        if ((unsigned)(wv >> 32) == (unsigned)t) break;
      }
      h_lds[tid] = __uint_as_float((unsigned)wv);
    }
    __syncthreads();  // A: h_lds complete
    float hv[16];
    #pragma unroll
    for (int e = 0; e < 16; e++) hv[e] = h_lds[rb + 32 * e];  // bank rb, bcast
    // partial matvec: 16 rows x 8 cols
    float zp[8];
    #pragma unroll
    for (int c = 0; c < 8; c++) zp[c] = 0.0f;
    #pragma unroll
    for (int e = 0; e < 16; e++) {
      #pragma unroll
      for (int c = 0; c < 8; c++) zp[c] += hv[e] * u[e][c];
    }
    // reduce over the 32 threads sharing cb (xor masks stay in 32-lane group)
    #pragma unroll
    for (int m = 1; m < 32; m <<= 1) {
      #pragma unroll
      for (int c = 0; c < 8; c++) zp[c] += __shfl_xor(zp[c], m, 64);
    }
    if (rb == 0) {
      *(float4*)&z_lds[cb * 8]     = make_float4(zp[0], zp[1], zp[2], zp[3]);
      *(float4*)&z_lds[cb * 8 + 4] = make_float4(zp[4], zp[5], zp[6], zp[7]);
    }
    __syncthreads();  // B: z_lds complete
    if (tid < 32) {  // gates for unit u = tid
      float zi = z_lds[tid]       + xzv0;
      float zf = z_lds[32 + tid]  + xzv1;
      float zg = z_lds[64 + tid]  + xzv2;
      float zo = z_lds[96 + tid]  + xzv3;
      float ig = sigm(zi), fg = sigm(zf), gg = tanh_fast(zg), og = sigm(zo);
      creg = fg * creg + ig * gg;
      float h = og * tanh_fast(creg);
      hs[(size_t)t * 512 + wg * 32 + tid] = f2bf(h);
      uint64_t pk = ((uint64_t)(unsigned)(t + 1) << 32) | (uint64_t)__float_as_uint(h);
      __hip_atomic_store(&hb[(size_t)((t + 1) & 1) * 512 + wg * 32 + tid], pk,
                         __ATOMIC_RELAXED, __HIP_MEMORY_SCOPE_AGENT);
    }
  }
}

// ---------------------------------------------------------------------------
// Kernel 4: logits = hs @ Wl + bl, bf16 MFMA 16x16x32, 128x128 tile, 4 waves.
// Output remap: gemm row t -> out row (t%256)*8 + t/256.
// ---------------------------------------------------------------------------
__global__ __launch_bounds__(256) void logits_kernel(
    const unsigned short* __restrict__ hs, const unsigned short* __restrict__ Wlt,
    const float* __restrict__ bl, float* __restrict__ out)
{
  __shared__ unsigned short As[128][40];  // [row][k] +8 pad
  __shared__ unsigned short Bs[128][40];  // [col][k] +8 pad
  const int tid = threadIdx.x;
  const int bx = blockIdx.x, by = blockIdx.y;
  const int lane = tid & 63, w = tid >> 6;
  const int wr = w >> 1, wc = w & 1;

  f32x4 acc[4][4];
  #pragma unroll
  for (int i = 0; i < 4; i++) {
    #pragma unroll
    for (int j = 0; j < 4; j++) acc[i][j] = (f32x4){0.0f, 0.0f, 0.0f, 0.0f};
  }

  for (int kk = 0; kk < 512; kk += 32) {
    #pragma unroll
    for (int i = 0; i < 2; i++) {
      int chunk = tid * 2 + i;          // 512 chunks of 16B
      int r = chunk >> 2, c8 = (chunk & 3) * 8;
      *(uint4*)&As[r][c8] = *(const uint4*)&hs[(size_t)(by * 128 + r) * 512 + kk + c8];
      *(uint4*)&Bs[r][c8] = *(const uint4*)&Wlt[(size_t)(bx * 128 + r) * 512 + kk + c8];
    }
    __syncthreads();
    short8 af[4], bf[4];
    #pragma unroll
    for (int fr = 0; fr < 4; fr++)
      af[fr] = *(const short8*)&As[wr * 64 + fr * 16 + (lane & 15)][(lane >> 4) * 8];
    #pragma unroll
    for (int fc = 0; fc < 4; fc++)
      bf[fc] = *(const short8*)&Bs[wc * 64 + fc * 16 + (lane & 15)][(lane >> 4) * 8];
    #pragma unroll
    for (int fr = 0; fr < 4; fr++) {
      #pragma unroll
      for (int fc = 0; fc < 4; fc++)
        acc[fr][fc] = __builtin_amdgcn_mfma_f32_16x16x32_bf16(af[fr], bf[fc], acc[fr][fc], 0, 0, 0);
    }
    __syncthreads();
  }

  #pragma unroll
  for (int fc = 0; fc < 4; fc++) {
    int col = bx * 128 + wc * 64 + fc * 16 + (lane & 15);
    float blv = bl[col];
    #pragma unroll
    for (int fr = 0; fr < 4; fr++) {
      int row0 = by * 128 + wr * 64 + fr * 16 + (lane >> 4) * 4;
      #pragma unroll
      for (int j = 0; j < 4; j++) {
        int row = row0 + j;
        int orow = (row & 255) * 8 + (row >> 8);
        out[(size_t)orow * VOCAB + col] = acc[fr][fc][j] + blv;
      }
    }
  }
}

// ---------------------------------------------------------------------------
extern "C" void kernel_launch(void* const* d_in, const int* in_sizes, int n_in,
                              void* d_out, int out_size, void* d_ws, size_t ws_size,
                              hipStream_t stream)
{
  const float* ctx = (const float*)d_in[0];
  const float* Wm  = (const float*)d_in[1];
  const float* bm  = (const float*)d_in[2];
  const float* W   = (const float*)d_in[3];
  const float* U   = (const float*)d_in[4];
  const float* b   = (const float*)d_in[5];
  const float* Wl  = (const float*)d_in[6];
  const float* bl  = (const float*)d_in[7];
  float* out = (float*)d_out;

  char* ws = (char*)d_ws;
  uint64_t* hb        = (uint64_t*)ws;                                  // 8 KB (2x512 u64)
  float* xz           = (float*)(ws + 65536);                           // 2 MB
  unsigned short* hs  = (unsigned short*)(ws + 65536 + (1 << 21));      // 2 MB
  unsigned short* Wlt = (unsigned short*)(ws + 65536 + (2 << 21));      // 32.77 MB

  hipMemsetAsync(hb, 0, 8192, stream);  // h_0 = 0 with counter 0 (both parities)
  prep_kernel<<<dim3(64), dim3(512), 0, stream>>>(ctx, Wm, bm, W, b, xz);
  wl_convert_kernel<<<dim3(125), dim3(256), 0, stream>>>(Wl, Wlt);

  void* args[] = { (void*)&xz, (void*)&U, (void*)&hb, (void*)&hs };
  hipLaunchCooperativeKernel((void*)lstm_kernel, dim3(NWG), dim3(512), args, 0, stream);

  logits_kernel<<<dim3(250, 16), dim3(256), 0, stream>>>(hs, Wlt, bl, out);
}